// Round 7
// baseline (169.757 us; speedup 1.0000x reference)
//
#include <hip/hip_runtime.h>
#include <math.h>

#define NDST 50000
#define NSRC 50000
#define NEDGE 800000
#define DF 128

#define NBUK 1563          // ceil(NDST/32): dst bucket = dst >> 5
#define NCH 128            // edge chunks
#define EPC (NEDGE / NCH)  // 6250 edges per chunk
#define HN (NBUK * NCH)    // 200064 histogram cells
#define CAP 1536           // per-chunk LDS sort capacity (avg bucket ~512)

typedef __attribute__((ext_vector_type(4))) float f32x4;
typedef __attribute__((ext_vector_type(8))) short bf16x8;

__device__ __forceinline__ ushort f2bf(float f) {
    union { float f; unsigned int u; } c; c.f = f;
    unsigned int u = c.u;
    unsigned int r = (u + 0x7fffu + ((u >> 16) & 1u)) >> 16;   // RNE
    return (ushort)r;
}
__device__ __forceinline__ float bflo(unsigned int u) {
    union { unsigned int u; float f; } c; c.u = u << 16; return c.f;
}
__device__ __forceinline__ float bfhi(unsigned int u) {
    union { unsigned int u; float f; } c; c.u = u & 0xffff0000u; return c.f;
}

// ---------------- zero histogram (hipMemsetAsync's fill kernel took 40us!) ----------------
__global__ void zero_hist(uint4* __restrict__ hist4) {
    int i = blockIdx.x * 256 + threadIdx.x;
    if (i < HN / 4) hist4[i] = make_uint4(0, 0, 0, 0);
}

// ---------------- histogram: hist[bucket*NCH + chunk] ----------------
__global__ void hist_k(const int* __restrict__ dst_idx, int* __restrict__ hist) {
    int c = blockIdx.x, tid = threadIdx.x;
    int base = c * EPC;
    for (int e = base + tid; e < base + EPC; e += 256)
        atomicAdd(&hist[(dst_idx[e] >> 5) * NCH + c], 1);
}

// ---------------- generic 3-phase exclusive scan ----------------
__global__ void scan_bsums(const int* __restrict__ a, int* __restrict__ bsum, int n) {
    __shared__ int ws[4];
    int i = blockIdx.x * 256 + threadIdx.x;
    int v = (i < n) ? a[i] : 0;
    #pragma unroll
    for (int off = 32; off > 0; off >>= 1) v += __shfl_down(v, off, 64);
    if ((threadIdx.x & 63) == 0) ws[threadIdx.x >> 6] = v;
    __syncthreads();
    if (threadIdx.x == 0) bsum[blockIdx.x] = ws[0] + ws[1] + ws[2] + ws[3];
}

__global__ __launch_bounds__(256)
void scan_mid(const int* __restrict__ bsum, int* __restrict__ bpre, int nb) {
    __shared__ int part[256];
    int t = threadIdx.x;
    int ch = (nb + 255) / 256;
    int lo = t * ch, hi = min(nb, lo + ch);
    int s = 0;
    for (int i = lo; i < hi; ++i) s += bsum[i];
    part[t] = s;
    __syncthreads();
    for (int off = 1; off < 256; off <<= 1) {
        int v = (t >= off) ? part[t - off] : 0;
        __syncthreads();
        part[t] += v;
        __syncthreads();
    }
    int run = (t == 0) ? 0 : part[t - 1];
    for (int i = lo; i < hi; ++i) { bpre[i] = run; run += bsum[i]; }
}

__global__ __launch_bounds__(256)
void scan_final(const int* __restrict__ a, const int* __restrict__ bpre,
                int* __restrict__ out, int n) {
    __shared__ int s[256];
    int b = blockIdx.x, t = threadIdx.x;
    int i = b * 256 + t;
    int v = (i < n) ? a[i] : 0;
    s[t] = v;
    __syncthreads();
    for (int off = 1; off < 256; off <<= 1) {
        int u = (t >= off) ? s[t - off] : 0;
        __syncthreads();
        s[t] += u;
        __syncthreads();
    }
    if (i < n) out[i] = bpre[b] + s[t] - v;
}

// ---------------- partition: bucket-grouped (dlow<<16 | src) pairs ----------------
__global__ __launch_bounds__(256)
void partition_k(const int* __restrict__ src_idx, const int* __restrict__ dst_idx,
                 const int* __restrict__ scanned, unsigned int* __restrict__ pairs) {
    __shared__ int offs_l[NBUK];
    int c = blockIdx.x, tid = threadIdx.x;
    for (int i = tid; i < NBUK; i += 256) offs_l[i] = scanned[i * NCH + c];
    __syncthreads();
    int base = c * EPC;
    for (int e = base + tid; e < base + EPC; e += 256) {
        int d = dst_idx[e];
        int pos = atomicAdd(&offs_l[d >> 5], 1);
        pairs[pos] = (unsigned int)src_idx[e] | ((unsigned int)(d & 31) << 16);
    }
}

// ---------------- feat_src -> bf16 (packed pairs) ----------------
__global__ void conv_fs(const float* __restrict__ fs, unsigned int* __restrict__ fs_b) {
    int i = blockIdx.x * 256 + threadIdx.x;
    if (i >= NSRC * DF / 4) return;
    float4 v = *(const float4*)(fs + (size_t)i * 4);
    unsigned int lo = (unsigned int)f2bf(v.x) | ((unsigned int)f2bf(v.y) << 16);
    unsigned int hi = (unsigned int)f2bf(v.z) | ((unsigned int)f2bf(v.w) << 16);
    *(uint2*)(fs_b + (size_t)i * 2) = make_uint2(lo, hi);
}

// ---------------- weight prep: f32 -> bf16, [c][k] ----------------
__global__ void prep_weights(const float* __restrict__ W2, const float* __restrict__ W1,
                             const float* __restrict__ W3,
                             ushort* __restrict__ Wz_b, ushort* __restrict__ W1_b,
                             ushort* __restrict__ W3_b) {
    int i = blockIdx.x * 256 + threadIdx.x;
    if (i < 128 * 256) {
        int c = i >> 8, k = i & 255;
        float v = (k < 128) ? (W2[c * 384 + k] + W2[c * 384 + 128 + k])
                            : W2[c * 384 + 128 + k];
        Wz_b[i] = f2bf(v);
    } else if (i < 128 * 256 + 128 * 128) {
        int j = i - 128 * 256;
        W1_b[j] = f2bf(W1[j]);
    } else if (i < 128 * 256 + 128 * 128 + 128 * 256) {
        int j = i - 128 * 256 - 128 * 128;
        W3_b[j] = f2bf(W3[j]);
    }
}

// ---------------- bucket aggregate: LDS counting-sort + REGISTER max/sum ----------------
__global__ __launch_bounds__(256)
void bucket_sort_agg(const unsigned int* __restrict__ fs_b,
                     const unsigned int* __restrict__ pairs,
                     const int* __restrict__ scanned,
                     unsigned int* __restrict__ mx_b, unsigned int* __restrict__ sm_b) {
    __shared__ int s_src[CAP];
    __shared__ int s_cnt[32], s_off[32], s_cur[32];
    int B = blockIdx.x, tid = threadIdx.x;
    int w = tid >> 6, lane = tid & 63;
    int s0 = scanned[B * NCH];
    int s1 = (B + 1 < NBUK) ? scanned[(B + 1) * NCH] : NEDGE;

    float mx0[8], mx1[8], sm0[8], sm1[8];
    #pragma unroll
    for (int j = 0; j < 8; ++j) {
        mx0[j] = -INFINITY; mx1[j] = -INFINITY; sm0[j] = 0.f; sm1[j] = 0.f;
    }

    for (int cs = s0; cs < s1; cs += CAP) {
        int n = min(CAP, s1 - cs);
        if (tid < 32) s_cnt[tid] = 0;
        __syncthreads();
        for (int i = tid; i < n; i += 256)
            atomicAdd(&s_cnt[(pairs[cs + i] >> 16) & 31u], 1);
        __syncthreads();
        if (tid < 32) {                      // wave 0: 32-wide shfl scan
            int v = s_cnt[tid];
            int incl = v;
            #pragma unroll
            for (int d = 1; d < 32; d <<= 1) {
                int o = __shfl_up(incl, d, 64);
                if (tid >= d) incl += o;
            }
            s_off[tid] = incl - v;
            s_cur[tid] = incl - v;
        }
        __syncthreads();
        for (int i = tid; i < n; i += 256) {
            unsigned int p = pairs[cs + i];
            int pos = atomicAdd(&s_cur[(p >> 16) & 31u], 1);
            s_src[pos] = (int)(p & 0xFFFFu);
        }
        __syncthreads();
        #pragma unroll
        for (int j = 0; j < 8; ++j) {
            int dl = w * 8 + j;
            int e = s_off[dl], eend = e + s_cnt[dl];
            for (; e + 3 < eend; e += 4) {          // 4 outstanding row loads
                int i0 = s_src[e], i1 = s_src[e + 1], i2 = s_src[e + 2], i3 = s_src[e + 3];
                unsigned int u0 = fs_b[(size_t)i0 * 64 + lane];
                unsigned int u1 = fs_b[(size_t)i1 * 64 + lane];
                unsigned int u2 = fs_b[(size_t)i2 * 64 + lane];
                unsigned int u3 = fs_b[(size_t)i3 * 64 + lane];
                float a0 = bflo(u0), c0 = bfhi(u0);
                float a1 = bflo(u1), c1 = bfhi(u1);
                float a2 = bflo(u2), c2 = bfhi(u2);
                float a3 = bflo(u3), c3 = bfhi(u3);
                mx0[j] = fmaxf(fmaxf(fmaxf(mx0[j], a0), a1), fmaxf(a2, a3));
                mx1[j] = fmaxf(fmaxf(fmaxf(mx1[j], c0), c1), fmaxf(c2, c3));
                sm0[j] += (a0 + a1) + (a2 + a3);
                sm1[j] += (c0 + c1) + (c2 + c3);
            }
            for (; e < eend; ++e) {
                unsigned int u = fs_b[(size_t)s_src[e] * 64 + lane];
                float a = bflo(u), c = bfhi(u);
                mx0[j] = fmaxf(mx0[j], a);
                mx1[j] = fmaxf(mx1[j], c);
                sm0[j] += a;
                sm1[j] += c;
            }
        }
        __syncthreads();                     // LDS reused next chunk
    }

    int base_d = B * 32;
    #pragma unroll
    for (int j = 0; j < 8; ++j) {
        int d = base_d + w * 8 + j;
        if (d >= NDST) continue;
        float m0 = mx0[j], m1 = mx1[j];
        if (m0 == -INFINITY) m0 = 0.f;       // zero-degree dst
        if (m1 == -INFINITY) m1 = 0.f;
        union { float f; unsigned int u; } c0, c1;
        c0.f = m0; c1.f = m1;                // maxima of bf16 values: exact truncation
        size_t o = (size_t)d * 64 + lane;
        mx_b[o] = (c0.u >> 16) | (c1.u & 0xFFFF0000u);
        sm_b[o] = (unsigned int)f2bf(sm0[j]) | ((unsigned int)f2bf(sm1[j]) << 16);
    }
}

// ---------------- MFMA bf16 GEMM + bias + relu ----------------
#define GBM 128
#define GBK 32
#define LDW 40

template <int ABF, int OBF>
__global__ __launch_bounds__(256)
void gemm_mfma(const void* __restrict__ a0v, int a0s,
               const void* __restrict__ a1v, int a1s,
               const ushort* __restrict__ Wb,
               const float* __restrict__ bias,
               void* __restrict__ Cv, int ldc, int coloff,
               int M, int K) {
    __shared__ ushort As[GBM * LDW];
    __shared__ ushort Ws[128 * LDW];
    int tid = threadIdx.x;
    int bm = blockIdx.x * GBM;
    int wid = tid >> 6, lane = tid & 63;
    int wm = (wid & 1) * 64, wn = (wid >> 1) * 64;
    int lrow = lane & 15, lk8 = (lane >> 4) * 8;

    f32x4 acc[4][4];
    #pragma unroll
    for (int i = 0; i < 4; ++i)
        #pragma unroll
        for (int j = 0; j < 4; ++j)
            acc[i][j] = (f32x4){0.f, 0.f, 0.f, 0.f};

    int sr = tid >> 1;
    int skh = (tid & 1) * 16;

    for (int k0 = 0; k0 < K; k0 += GBK) {
        int part = k0 >> 7;
        int kl = (k0 & 127) + skh;
        int m = bm + sr;
        uint4 w0, w1;
        if (ABF) {
            const ushort* ap = part ? (const ushort*)a1v : (const ushort*)a0v;
            int as = part ? a1s : a0s;
            if (m < M) {
                const ushort* p = ap + (size_t)m * as + kl;
                w0 = *(const uint4*)p;
                w1 = *(const uint4*)(p + 8);
            } else {
                w0 = make_uint4(0, 0, 0, 0); w1 = w0;
            }
        } else {
            const float* ap = part ? (const float*)a1v : (const float*)a0v;
            int as = part ? a1s : a0s;
            unsigned int pk[8];
            if (m < M) {
                const float* p = ap + (size_t)m * as + kl;
                #pragma unroll
                for (int j = 0; j < 8; ++j) {
                    float x = p[2 * j], y = p[2 * j + 1];
                    pk[j] = (unsigned int)f2bf(x) | ((unsigned int)f2bf(y) << 16);
                }
            } else {
                #pragma unroll
                for (int j = 0; j < 8; ++j) pk[j] = 0;
            }
            w0 = make_uint4(pk[0], pk[1], pk[2], pk[3]);
            w1 = make_uint4(pk[4], pk[5], pk[6], pk[7]);
        }
        *(uint4*)&As[sr * LDW + skh] = w0;
        *(uint4*)&As[sr * LDW + skh + 8] = w1;

        const ushort* wp = Wb + (size_t)sr * K + k0 + skh;
        uint4 v0 = *(const uint4*)wp;
        uint4 v1 = *(const uint4*)(wp + 8);
        *(uint4*)&Ws[sr * LDW + skh] = v0;
        *(uint4*)&Ws[sr * LDW + skh + 8] = v1;
        __syncthreads();

        bf16x8 af[4], bfr[4];
        #pragma unroll
        for (int mi = 0; mi < 4; ++mi)
            af[mi] = *(const bf16x8*)&As[(wm + mi * 16 + lrow) * LDW + lk8];
        #pragma unroll
        for (int ni = 0; ni < 4; ++ni)
            bfr[ni] = *(const bf16x8*)&Ws[(wn + ni * 16 + lrow) * LDW + lk8];
        #pragma unroll
        for (int mi = 0; mi < 4; ++mi)
            #pragma unroll
            for (int ni = 0; ni < 4; ++ni)
                acc[mi][ni] = __builtin_amdgcn_mfma_f32_16x16x32_bf16(
                    af[mi], bfr[ni], acc[mi][ni], 0, 0, 0);
        __syncthreads();
    }

    int rbase = (lane >> 4) * 4;
    #pragma unroll
    for (int ni = 0; ni < 4; ++ni) {
        int n = wn + ni * 16 + lrow;
        float bv = bias[n];
        #pragma unroll
        for (int mi = 0; mi < 4; ++mi) {
            #pragma unroll
            for (int r = 0; r < 4; ++r) {
                int m = bm + wm + mi * 16 + rbase + r;
                if (m < M) {
                    float v = fmaxf(acc[mi][ni][r] + bv, 0.f);
                    if (OBF) ((ushort*)Cv)[(size_t)m * ldc + coloff + n] = f2bf(v);
                    else     ((float*)Cv)[(size_t)m * ldc + coloff + n] = v;
                }
            }
        }
    }
}

extern "C" void kernel_launch(void* const* d_in, const int* in_sizes, int n_in,
                              void* d_out, int out_size, void* d_ws, size_t ws_size,
                              hipStream_t stream) {
    const float* feat_src = (const float*)d_in[0];
    const float* feat_dst = (const float*)d_in[1];
    const float* W1 = (const float*)d_in[2];
    const float* b1 = (const float*)d_in[3];
    const float* W2 = (const float*)d_in[4];
    const float* b2 = (const float*)d_in[5];
    const float* W3 = (const float*)d_in[6];
    const float* b3 = (const float*)d_in[7];
    const int* src_idx = (const int*)d_in[8];
    const int* dst_idx = (const int*)d_in[9];

    float* out = (float*)d_out;

    unsigned int* fs_b = (unsigned int*)d_ws;                 // NSRC*64 u32
    unsigned int* mx_b = fs_b + (size_t)NSRC * 64;            // NDST*64 u32
    unsigned int* sm_b = mx_b + (size_t)NDST * 64;            // NDST*64 u32
    ushort* h_b  = (ushort*)(sm_b + (size_t)NDST * 64);       // NDST*256 bf16
    ushort* Wz_b = h_b + (size_t)NDST * 256;                  // 128*256
    ushort* W1_b = Wz_b + 128 * 256;                          // 128*128
    ushort* W3_b = W1_b + 128 * 128;                          // 128*256
    int* hist    = (int*)(W3_b + 128 * 256);                  // HN (16B aligned)
    int* scanned = hist + HN;                                 // HN
    int* bsum    = scanned + HN;                              // 1024
    int* bpre    = bsum + 1024;                               // 1024
    unsigned int* pairs = (unsigned int*)(bpre + 1024);       // NEDGE

    const int NBH = (HN + 255) / 256;   // 782 scan blocks

    // bucket histogram + scan + partition
    zero_hist<<<(HN / 4 + 255) / 256, 256, 0, stream>>>((uint4*)hist);
    hist_k<<<NCH, 256, 0, stream>>>(dst_idx, hist);
    scan_bsums<<<NBH, 256, 0, stream>>>(hist, bsum, HN);
    scan_mid<<<1, 256, 0, stream>>>(bsum, bpre, NBH);
    scan_final<<<NBH, 256, 0, stream>>>(hist, bpre, scanned, HN);
    partition_k<<<NCH, 256, 0, stream>>>(src_idx, dst_idx, scanned, pairs);

    // conversions / weight prep
    conv_fs<<<(NSRC * DF / 4 + 255) / 256, 256, 0, stream>>>(feat_src, fs_b);
    prep_weights<<<(128 * 256 * 2 + 128 * 128 + 255) / 256, 256, 0, stream>>>(
        W2, W1, W3, Wz_b, W1_b, W3_b);

    // z1 = feat_dst @ W1^T + b1, relu -> h_b[:, 128:256]
    dim3 ggrid((NDST + GBM - 1) / GBM, 1);
    gemm_mfma<0, 1><<<ggrid, 256, 0, stream>>>(feat_dst, DF, nullptr, 0,
                                               W1_b, b1, h_b, 256, 128, NDST, 128);

    // aggregation: LDS-sorted bucket, register accumulation
    bucket_sort_agg<<<NBUK, 256, 0, stream>>>(fs_b, pairs, scanned, mx_b, sm_b);

    // z2 = [mx|sm] @ Wz^T + b2, relu -> h_b[:, 0:128]
    gemm_mfma<1, 1><<<ggrid, 256, 0, stream>>>(mx_b, DF, sm_b, DF,
                                               Wz_b, b2, h_b, 256, 0, NDST, 256);
    // out = relu(h @ W3^T + b3)
    gemm_mfma<1, 0><<<ggrid, 256, 0, stream>>>(h_b, 256, h_b + 128, 256,
                                               W3_b, b3, out, DF, 0, NDST, 256);
}

// Round 8
// 146.571 us; speedup vs baseline: 1.1582x; 1.1582x over previous
//
#include <hip/hip_runtime.h>
#include <math.h>

#define NDST 50000
#define NSRC 50000
#define NEDGE 800000
#define DF 128

#define NBUK 1563          // ceil(NDST/32): dst bucket = dst >> 5
#define NCH 128            // edge chunks
#define EPC (NEDGE / NCH)  // 6250 edges per chunk
#define HN (NBUK * NCH)    // 200064 histogram cells
#define CAP 1536           // per-chunk LDS sort capacity

typedef __attribute__((ext_vector_type(4))) float f32x4;
typedef __attribute__((ext_vector_type(8))) short bf16x8;

__device__ __forceinline__ ushort f2bf(float f) {
    union { float f; unsigned int u; } c; c.f = f;
    unsigned int u = c.u;
    unsigned int r = (u + 0x7fffu + ((u >> 16) & 1u)) >> 16;   // RNE
    return (ushort)r;
}
__device__ __forceinline__ float bflo(unsigned int u) {
    union { unsigned int u; float f; } c; c.u = u << 16; return c.f;
}
__device__ __forceinline__ float bfhi(unsigned int u) {
    union { unsigned int u; float f; } c; c.u = u & 0xffff0000u; return c.f;
}

// ---------------- prep_all: conv_fs + zero_hist + weight prep in one launch ----------------
#define NB_CONV 6250       // NSRC*DF/4/256
#define NB_ZERO 196        // ceil(HN/4/256)
#define NB_PREP 320        // ceil((2*128*256+128*128)/256)

__global__ void prep_all(const float* __restrict__ fs, unsigned int* __restrict__ fs_b,
                         uint4* __restrict__ hist4,
                         const float* __restrict__ W2, const float* __restrict__ W1,
                         const float* __restrict__ W3,
                         ushort* __restrict__ Wz_b, ushort* __restrict__ W1_b,
                         ushort* __restrict__ W3_b) {
    int b = blockIdx.x, tid = threadIdx.x;
    if (b < NB_CONV) {
        int i = b * 256 + tid;                    // 4 floats -> 2 uints
        float4 v = *(const float4*)(fs + (size_t)i * 4);
        unsigned int lo = (unsigned int)f2bf(v.x) | ((unsigned int)f2bf(v.y) << 16);
        unsigned int hi = (unsigned int)f2bf(v.z) | ((unsigned int)f2bf(v.w) << 16);
        *(uint2*)(fs_b + (size_t)i * 2) = make_uint2(lo, hi);
    } else if (b < NB_CONV + NB_ZERO) {
        int i = (b - NB_CONV) * 256 + tid;
        if (i < HN / 4) hist4[i] = make_uint4(0, 0, 0, 0);
    } else {
        int i = (b - NB_CONV - NB_ZERO) * 256 + tid;
        if (i < 128 * 256) {
            int c = i >> 8, k = i & 255;
            float v = (k < 128) ? (W2[c * 384 + k] + W2[c * 384 + 128 + k])
                                : W2[c * 384 + 128 + k];
            Wz_b[i] = f2bf(v);
        } else if (i < 128 * 256 + 128 * 128) {
            int j = i - 128 * 256;
            W1_b[j] = f2bf(W1[j]);
        } else if (i < 128 * 256 + 128 * 128 + 128 * 256) {
            int j = i - 128 * 256 - 128 * 128;
            W3_b[j] = f2bf(W3[j]);
        }
    }
}

// ---------------- histogram: hist[bucket*NCH + chunk] ----------------
__global__ void hist_k(const int* __restrict__ dst_idx, int* __restrict__ hist) {
    int c = blockIdx.x, tid = threadIdx.x;
    int base = c * EPC;
    for (int e = base + tid; e < base + EPC; e += 256)
        atomicAdd(&hist[(dst_idx[e] >> 5) * NCH + c], 1);
}

// ---------------- generic 3-phase exclusive scan ----------------
__global__ void scan_bsums(const int* __restrict__ a, int* __restrict__ bsum, int n) {
    __shared__ int ws[4];
    int i = blockIdx.x * 256 + threadIdx.x;
    int v = (i < n) ? a[i] : 0;
    #pragma unroll
    for (int off = 32; off > 0; off >>= 1) v += __shfl_down(v, off, 64);
    if ((threadIdx.x & 63) == 0) ws[threadIdx.x >> 6] = v;
    __syncthreads();
    if (threadIdx.x == 0) bsum[blockIdx.x] = ws[0] + ws[1] + ws[2] + ws[3];
}

__global__ __launch_bounds__(256)
void scan_mid(const int* __restrict__ bsum, int* __restrict__ bpre, int nb) {
    __shared__ int part[256];
    int t = threadIdx.x;
    int ch = (nb + 255) / 256;
    int lo = t * ch, hi = min(nb, lo + ch);
    int s = 0;
    for (int i = lo; i < hi; ++i) s += bsum[i];
    part[t] = s;
    __syncthreads();
    for (int off = 1; off < 256; off <<= 1) {
        int v = (t >= off) ? part[t - off] : 0;
        __syncthreads();
        part[t] += v;
        __syncthreads();
    }
    int run = (t == 0) ? 0 : part[t - 1];
    for (int i = lo; i < hi; ++i) { bpre[i] = run; run += bsum[i]; }
}

__global__ __launch_bounds__(256)
void scan_final(const int* __restrict__ a, const int* __restrict__ bpre,
                int* __restrict__ out, int n) {
    __shared__ int s[256];
    int b = blockIdx.x, t = threadIdx.x;
    int i = b * 256 + t;
    int v = (i < n) ? a[i] : 0;
    s[t] = v;
    __syncthreads();
    for (int off = 1; off < 256; off <<= 1) {
        int u = (t >= off) ? s[t - off] : 0;
        __syncthreads();
        s[t] += u;
        __syncthreads();
    }
    if (i < n) out[i] = bpre[b] + s[t] - v;
}

// ---------------- partition: bucket-grouped (dlow<<16 | src) pairs ----------------
__global__ __launch_bounds__(256)
void partition_k(const int* __restrict__ src_idx, const int* __restrict__ dst_idx,
                 const int* __restrict__ scanned, unsigned int* __restrict__ pairs) {
    __shared__ int offs_l[NBUK];
    int c = blockIdx.x, tid = threadIdx.x;
    for (int i = tid; i < NBUK; i += 256) offs_l[i] = scanned[i * NCH + c];
    __syncthreads();
    int base = c * EPC;
    for (int e = base + tid; e < base + EPC; e += 256) {
        int d = dst_idx[e];
        int pos = atomicAdd(&offs_l[d >> 5], 1);
        pairs[pos] = (unsigned int)src_idx[e] | ((unsigned int)(d & 31) << 16);
    }
}

// ---------------- bucket aggregate: LDS counting-sort + REGISTER max/sum ----------------
__global__ __launch_bounds__(256)
void bucket_sort_agg(const unsigned int* __restrict__ fs_b,
                     const unsigned int* __restrict__ pairs,
                     const int* __restrict__ scanned,
                     unsigned int* __restrict__ mx_b, unsigned int* __restrict__ sm_b) {
    __shared__ int s_src[CAP];
    __shared__ int s_cnt[32], s_off[32], s_cur[32];
    int B = blockIdx.x, tid = threadIdx.x;
    int w = tid >> 6, lane = tid & 63;
    int s0 = scanned[B * NCH];
    int s1 = (B + 1 < NBUK) ? scanned[(B + 1) * NCH] : NEDGE;

    float mx0[8], mx1[8], sm0[8], sm1[8];
    #pragma unroll
    for (int j = 0; j < 8; ++j) {
        mx0[j] = -INFINITY; mx1[j] = -INFINITY; sm0[j] = 0.f; sm1[j] = 0.f;
    }

    for (int cs = s0; cs < s1; cs += CAP) {
        int n = min(CAP, s1 - cs);
        if (tid < 32) s_cnt[tid] = 0;
        __syncthreads();
        for (int i = tid; i < n; i += 256)
            atomicAdd(&s_cnt[(pairs[cs + i] >> 16) & 31u], 1);
        __syncthreads();
        if (tid < 32) {                      // wave 0: 32-wide shfl scan
            int v = s_cnt[tid];
            int incl = v;
            #pragma unroll
            for (int d = 1; d < 32; d <<= 1) {
                int o = __shfl_up(incl, d, 64);
                if (tid >= d) incl += o;
            }
            s_off[tid] = incl - v;
            s_cur[tid] = incl - v;
        }
        __syncthreads();
        for (int i = tid; i < n; i += 256) {
            unsigned int p = pairs[cs + i];
            int pos = atomicAdd(&s_cur[(p >> 16) & 31u], 1);
            s_src[pos] = (int)(p & 0xFFFFu);
        }
        __syncthreads();
        #pragma unroll
        for (int j = 0; j < 8; ++j) {
            int dl = w * 8 + j;
            int e = s_off[dl], eend = e + s_cnt[dl];
            for (; e + 3 < eend; e += 4) {          // 4 outstanding row loads
                int i0 = s_src[e], i1 = s_src[e + 1], i2 = s_src[e + 2], i3 = s_src[e + 3];
                unsigned int u0 = fs_b[(size_t)i0 * 64 + lane];
                unsigned int u1 = fs_b[(size_t)i1 * 64 + lane];
                unsigned int u2 = fs_b[(size_t)i2 * 64 + lane];
                unsigned int u3 = fs_b[(size_t)i3 * 64 + lane];
                float a0 = bflo(u0), c0 = bfhi(u0);
                float a1 = bflo(u1), c1 = bfhi(u1);
                float a2 = bflo(u2), c2 = bfhi(u2);
                float a3 = bflo(u3), c3 = bfhi(u3);
                mx0[j] = fmaxf(fmaxf(fmaxf(mx0[j], a0), a1), fmaxf(a2, a3));
                mx1[j] = fmaxf(fmaxf(fmaxf(mx1[j], c0), c1), fmaxf(c2, c3));
                sm0[j] += (a0 + a1) + (a2 + a3);
                sm1[j] += (c0 + c1) + (c2 + c3);
            }
            for (; e < eend; ++e) {
                unsigned int u = fs_b[(size_t)s_src[e] * 64 + lane];
                float a = bflo(u), c = bfhi(u);
                mx0[j] = fmaxf(mx0[j], a);
                mx1[j] = fmaxf(mx1[j], c);
                sm0[j] += a;
                sm1[j] += c;
            }
        }
        __syncthreads();                     // LDS reused next chunk
    }

    int base_d = B * 32;
    #pragma unroll
    for (int j = 0; j < 8; ++j) {
        int d = base_d + w * 8 + j;
        if (d >= NDST) continue;
        float m0 = mx0[j], m1 = mx1[j];
        if (m0 == -INFINITY) m0 = 0.f;       // zero-degree dst
        if (m1 == -INFINITY) m1 = 0.f;
        union { float f; unsigned int u; } c0, c1;
        c0.f = m0; c1.f = m1;                // maxima of bf16 values: exact truncation
        size_t o = (size_t)d * 64 + lane;
        mx_b[o] = (c0.u >> 16) | (c1.u & 0xFFFF0000u);
        sm_b[o] = (unsigned int)f2bf(sm0[j]) | ((unsigned int)f2bf(sm1[j]) << 16);
    }
}

// ---------------- fused MLP: z2|z1 -> h (LDS) -> out, one kernel ----------------
// Block: 64 output rows, 256 threads (4 waves, 2x2 wave grid, 32x64 per wave).
// Phase A1: h[:,0:128]  = relu([mx|sm] @ Wz^T + b2), K=256
// Phase A2: h[:,128:256]= relu(feat_dst @ W1^T + b1), K=128 (f32 -> bf16 staging)
// Phase B : out = relu(h @ W3^T + b3), K=256, A from LDS h
#define BM2 64
#define LDW 40     // staging tile row stride (ushorts): 80B -> 2-way conflicts (free)
#define LDH 264    // h tile row stride (ushorts): 528B -> 2-way conflicts (free)

__global__ __launch_bounds__(256)
void mlp_fused(const ushort* __restrict__ mxa, const ushort* __restrict__ sma,
               const float* __restrict__ feat_dst,
               const ushort* __restrict__ Wz_b, const ushort* __restrict__ W1_b,
               const ushort* __restrict__ W3_b,
               const float* __restrict__ b1, const float* __restrict__ b2,
               const float* __restrict__ b3,
               float* __restrict__ out) {
    __shared__ ushort Hs[BM2 * LDH];     // 33.8 KB
    __shared__ ushort As[BM2 * LDW];     // 5.1 KB
    __shared__ ushort Ws[128 * LDW];     // 10.2 KB
    int tid = threadIdx.x;
    int bm = blockIdx.x * BM2;
    int wid = tid >> 6, lane = tid & 63;
    int wm = (wid & 1) * 32, wn = (wid >> 1) * 64;
    int lrow = lane & 15, lk8 = (lane >> 4) * 8;
    int rbase = (lane >> 4) * 4;

    int sra = tid >> 2, ska = (tid & 3) * 8;      // A stage: 64 rows x 32k, 8 bf16/thr
    int srw = tid >> 1, skw = (tid & 1) * 16;     // W stage: 128 rows x 32k, 16 bf16/thr

    f32x4 acc[2][4];

    // ---------- phase A1 + A2 ----------
    #pragma unroll
    for (int half = 0; half < 2; ++half) {
        #pragma unroll
        for (int i = 0; i < 2; ++i)
            #pragma unroll
            for (int j = 0; j < 4; ++j)
                acc[i][j] = (f32x4){0.f, 0.f, 0.f, 0.f};
        int K = half ? 128 : 256;
        const ushort* Wb = half ? W1_b : Wz_b;
        for (int k0 = 0; k0 < K; k0 += 32) {
            int m = bm + sra;
            uint4 av = make_uint4(0, 0, 0, 0);
            if (m < NDST) {
                if (half == 0) {
                    const ushort* ap = (k0 < 128) ? mxa : sma;
                    av = *(const uint4*)(ap + (size_t)m * 128 + (k0 & 127) + ska);
                } else {
                    const float* p = feat_dst + (size_t)m * 128 + k0 + ska;
                    unsigned int pk[4];
                    #pragma unroll
                    for (int j = 0; j < 4; ++j) {
                        float x = p[2 * j], y = p[2 * j + 1];
                        pk[j] = (unsigned int)f2bf(x) | ((unsigned int)f2bf(y) << 16);
                    }
                    av = make_uint4(pk[0], pk[1], pk[2], pk[3]);
                }
            }
            *(uint4*)&As[sra * LDW + ska] = av;

            const ushort* wp = Wb + (size_t)srw * K + k0 + skw;
            *(uint4*)&Ws[srw * LDW + skw] = *(const uint4*)wp;
            *(uint4*)&Ws[srw * LDW + skw + 8] = *(const uint4*)(wp + 8);
            __syncthreads();

            bf16x8 af[2], bfr[4];
            #pragma unroll
            for (int mi = 0; mi < 2; ++mi)
                af[mi] = *(const bf16x8*)&As[(wm + mi * 16 + lrow) * LDW + lk8];
            #pragma unroll
            for (int ni = 0; ni < 4; ++ni)
                bfr[ni] = *(const bf16x8*)&Ws[(wn + ni * 16 + lrow) * LDW + lk8];
            #pragma unroll
            for (int mi = 0; mi < 2; ++mi)
                #pragma unroll
                for (int ni = 0; ni < 4; ++ni)
                    acc[mi][ni] = __builtin_amdgcn_mfma_f32_16x16x32_bf16(
                        af[mi], bfr[ni], acc[mi][ni], 0, 0, 0);
            __syncthreads();
        }
        // epilogue -> Hs[:, half*128 + n], bias + relu, bf16
        const float* bias = half ? b1 : b2;
        #pragma unroll
        for (int ni = 0; ni < 4; ++ni) {
            int n = wn + ni * 16 + lrow;
            float bv = bias[n];
            #pragma unroll
            for (int mi = 0; mi < 2; ++mi)
                #pragma unroll
                for (int r = 0; r < 4; ++r) {
                    float v = fmaxf(acc[mi][ni][r] + bv, 0.f);
                    Hs[(wm + mi * 16 + rbase + r) * LDH + half * 128 + n] = f2bf(v);
                }
        }
    }
    __syncthreads();   // Hs complete before phase B reads

    // ---------- phase B: out = relu(h @ W3^T + b3) ----------
    #pragma unroll
    for (int i = 0; i < 2; ++i)
        #pragma unroll
        for (int j = 0; j < 4; ++j)
            acc[i][j] = (f32x4){0.f, 0.f, 0.f, 0.f};
    for (int k0 = 0; k0 < 256; k0 += 32) {
        const ushort* wp = W3_b + (size_t)srw * 256 + k0 + skw;
        *(uint4*)&Ws[srw * LDW + skw] = *(const uint4*)wp;
        *(uint4*)&Ws[srw * LDW + skw + 8] = *(const uint4*)(wp + 8);
        __syncthreads();

        bf16x8 af[2], bfr[4];
        #pragma unroll
        for (int mi = 0; mi < 2; ++mi)
            af[mi] = *(const bf16x8*)&Hs[(wm + mi * 16 + lrow) * LDH + k0 + lk8];
        #pragma unroll
        for (int ni = 0; ni < 4; ++ni)
            bfr[ni] = *(const bf16x8*)&Ws[(wn + ni * 16 + lrow) * LDW + lk8];
        #pragma unroll
        for (int mi = 0; mi < 2; ++mi)
            #pragma unroll
            for (int ni = 0; ni < 4; ++ni)
                acc[mi][ni] = __builtin_amdgcn_mfma_f32_16x16x32_bf16(
                    af[mi], bfr[ni], acc[mi][ni], 0, 0, 0);
        __syncthreads();
    }
    #pragma unroll
    for (int ni = 0; ni < 4; ++ni) {
        int n = wn + ni * 16 + lrow;
        float bv = b3[n];
        #pragma unroll
        for (int mi = 0; mi < 2; ++mi)
            #pragma unroll
            for (int r = 0; r < 4; ++r) {
                int m = bm + wm + mi * 16 + rbase + r;
                if (m < NDST)
                    out[(size_t)m * 128 + n] = fmaxf(acc[mi][ni][r] + bv, 0.f);
            }
    }
}

extern "C" void kernel_launch(void* const* d_in, const int* in_sizes, int n_in,
                              void* d_out, int out_size, void* d_ws, size_t ws_size,
                              hipStream_t stream) {
    const float* feat_src = (const float*)d_in[0];
    const float* feat_dst = (const float*)d_in[1];
    const float* W1 = (const float*)d_in[2];
    const float* b1 = (const float*)d_in[3];
    const float* W2 = (const float*)d_in[4];
    const float* b2 = (const float*)d_in[5];
    const float* W3 = (const float*)d_in[6];
    const float* b3 = (const float*)d_in[7];
    const int* src_idx = (const int*)d_in[8];
    const int* dst_idx = (const int*)d_in[9];

    float* out = (float*)d_out;

    unsigned int* fs_b = (unsigned int*)d_ws;                 // NSRC*64 u32
    unsigned int* mx_b = fs_b + (size_t)NSRC * 64;            // NDST*64 u32
    unsigned int* sm_b = mx_b + (size_t)NDST * 64;            // NDST*64 u32
    ushort* Wz_b = (ushort*)(sm_b + (size_t)NDST * 64);       // 128*256
    ushort* W1_b = Wz_b + 128 * 256;                          // 128*128
    ushort* W3_b = W1_b + 128 * 128;                          // 128*256
    int* hist    = (int*)(W3_b + 128 * 256);                  // HN (16B aligned)
    int* scanned = hist + HN;                                 // HN
    int* bsum    = scanned + HN;                              // 1024
    int* bpre    = bsum + 1024;                               // 1024
    unsigned int* pairs = (unsigned int*)(bpre + 1024);       // NEDGE

    const int NBH = (HN + 255) / 256;   // 782 scan blocks

    // prep: feat_src->bf16, zero hist, weights->bf16 (one launch)
    prep_all<<<NB_CONV + NB_ZERO + NB_PREP, 256, 0, stream>>>(
        feat_src, fs_b, (uint4*)hist, W2, W1, W3, Wz_b, W1_b, W3_b);

    // bucket histogram + scan + partition
    hist_k<<<NCH, 256, 0, stream>>>(dst_idx, hist);
    scan_bsums<<<NBH, 256, 0, stream>>>(hist, bsum, HN);
    scan_mid<<<1, 256, 0, stream>>>(bsum, bpre, NBH);
    scan_final<<<NBH, 256, 0, stream>>>(hist, bpre, scanned, HN);
    partition_k<<<NCH, 256, 0, stream>>>(src_idx, dst_idx, scanned, pairs);

    // aggregation: LDS-sorted bucket, register accumulation
    bucket_sort_agg<<<NBUK, 256, 0, stream>>>(fs_b, pairs, scanned, mx_b, sm_b);

    // fused MLP: [mx|sm]->z2, feat_dst->z1, h in LDS, out = relu(h@W3^T+b3)
    mlp_fused<<<(NDST + BM2 - 1) / BM2, 256, 0, stream>>>(
        (const ushort*)mx_b, (const ushort*)sm_b, feat_dst,
        Wz_b, W1_b, W3_b, b1, b2, b3, out);
}